// Round 9
// baseline (551.092 us; speedup 1.0000x reference)
//
#include <hip/hip_runtime.h>
#include <hip/hip_bf16.h>
#include <math.h>

#define N_NODES 8192
#define IN_F    512
#define OUT_F   128
#define LRELU_A 0.2f
#define EPS_BN  1e-5f
#define MSH     40.0f                // static softmax shift (upper bound on lrelu(max s1+max s2))
#define NSPLIT  4
#define JSPAN   (N_NODES / NSPLIT)   // 2048
#define TILE_I  32                   // 2 i-blocks x 16; 4 waves = 2 i-blocks x 2 c-halves

typedef unsigned short u16;
typedef unsigned int   u32;
typedef unsigned long long u64;
typedef __attribute__((ext_vector_type(8))) short  short8;
typedef __attribute__((ext_vector_type(4))) float  floatx4;

__device__ __forceinline__ u16 f2bf_rtn(float x) {
    u32 u = __float_as_uint(x);
    return (u16)((u + 0x7fffu + ((u >> 16) & 1u)) >> 16);
}

// ---------------- adj -> bitmask (8 MB), pure HBM stream ----------------
// grid 2048 x 256 thr. wave = one row; 32 groups of 256 j; 1 KB coalesced read per load.
// bit layout per 256-j group: word (2c+h), bit l  <=>  j = g*256 + 4l + c  (ballot order)
__global__ __launch_bounds__(256) void k_pack(const int* __restrict__ adj, u32* __restrict__ mask) {
    const int t = threadIdx.x;
    const int lane = t & 63, wid = t >> 6;
    const int row = blockIdx.x * 4 + wid;
    const int* ap = adj + (size_t)row * N_NODES + lane * 4;
    u32* mp = mask + (size_t)row * 256;
    uint4 cur = *(const uint4*)(ap);
#pragma unroll 4
    for (int g = 0; g < 32; ++g) {
        uint4 nxt = cur;
        if (g + 1 < 32) nxt = *(const uint4*)(ap + (g + 1) * 256);
        u64 b0 = __ballot((int)cur.x > 0);
        u64 b1 = __ballot((int)cur.y > 0);
        u64 b2 = __ballot((int)cur.z > 0);
        u64 b3 = __ballot((int)cur.w > 0);
        if (lane < 4) {
            u64 v = (lane == 0) ? b0 : (lane == 1) ? b1 : (lane == 2) ? b2 : b3;
            *(u64*)(mp + g * 8 + lane * 2) = v;
        }
        cur = nxt;
    }
}

// ---------------- h = input @ hamilton(W); W staged in LDS ----------------
// grid 512 x 256 thr; block = 16 rows x 128 cols; thread = 1 row x 8 cols.
__global__ __launch_bounds__(256) void k_h(const float* __restrict__ inp, const float* __restrict__ W,
                                           const float* __restrict__ a,
                                           u16* __restrict__ hT, float* __restrict__ s1, float* __restrict__ s2,
                                           float* __restrict__ cs, float* __restrict__ cq) {
    __shared__ float Wl[128 * 128];      // 64 KB
    __shared__ float s1b[16], s2b[16];
    const int t = threadIdx.x;
    if (t < 16) { s1b[t] = 0.f; s2b[t] = 0.f; }
    if (blockIdx.x == 0 && t < OUT_F) { cs[t] = 0.f; cq[t] = 0.f; }
#pragma unroll
    for (int i = 0; i < 16; i++) {
        const int idx = t * 4 + i * 1024;
        *(float4*)&Wl[idx] = *(const float4*)&W[idx];
    }
    __syncthreads();
    const int rg = t >> 4, cg = t & 15;
    const int r = blockIdx.x * 16 + rg;
    const int b = cg >> 2, cc0 = (cg & 3) * 8;
    const u32 NEGMASK = 0x284Eu;
    float acc[8];
#pragma unroll
    for (int q = 0; q < 8; q++) acc[q] = 0.f;
    const float* row = inp + (size_t)r * IN_F;
    for (int k8 = 0; k8 < IN_F; k8 += 8) {
        const int p = k8 >> 7;
        const float sg = ((NEGMASK >> (b * 4 + p)) & 1u) ? -1.f : 1.f;
        const float* wbase = Wl + (b ^ p) * 32 + cc0;
        float4 x0 = *(const float4*)(row + k8);
        float4 x1 = *(const float4*)(row + k8 + 4);
        float xv[8] = {x0.x, x0.y, x0.z, x0.w, x1.x, x1.y, x1.z, x1.w};
#pragma unroll
        for (int dk = 0; dk < 8; dk++) {
            const int q = (k8 + dk) & 127;
            const float* wp = wbase + q * 128;
            float4 w0 = *(const float4*)wp;
            float4 w1 = *(const float4*)(wp + 4);
            const float av = xv[dk] * sg;
            acc[0] += av * w0.x; acc[1] += av * w0.y; acc[2] += av * w0.z; acc[3] += av * w0.w;
            acc[4] += av * w1.x; acc[5] += av * w1.y; acc[6] += av * w1.z; acc[7] += av * w1.w;
        }
    }
    float s1p = 0.f, s2p = 0.f;
#pragma unroll
    for (int q = 0; q < 8; q++) {
        const int c = (cg << 3) + q;
        hT[(size_t)c * N_NODES + r] = f2bf_rtn(acc[q]);
        s1p += acc[q] * a[c];
        s2p += acc[q] * a[OUT_F + c];
    }
    atomicAdd(&s1b[rg], s1p);
    atomicAdd(&s2b[rg], s2p);
    __syncthreads();
    if (t < 16) { s1[blockIdx.x * 16 + t] = s1b[t]; s2[blockIdx.x * 16 + t] = s2b[t]; }
}

// ---------------- MFMA attention: bitmask + direct-global B-frags, barrier-free j-loop ----------------
// grid (256, NSPLIT) x 256 thr. Block: 32 i x 128 c; wave: 16 i x 64 c (ib = wid>>1, ch = wid&1).
__global__ __launch_bounds__(256, 3) void k_att(const u32* __restrict__ mask, const u16* __restrict__ hT,
                                                const float* __restrict__ s1, const float* __restrict__ s2,
                                                float* __restrict__ Opart, float* __restrict__ Lpart) {
    __shared__ float s2s[JSPAN];   // 8 KB
    const int t = threadIdx.x;
    const int lane = t & 63, wid = t >> 6;
    const int quad = lane >> 4, n = lane & 15;
    const int ib = wid >> 1, ch = wid & 1;
    const int i0 = blockIdx.x * TILE_I;
    const int jbase = blockIdx.y * JSPAN;
    const int i_lane = i0 + ib * 16 + n;
    const float s1v = s1[i_lane];

    {   // stage s2 slice (8 KB)
        const int o = t * 8;
        *(float4*)&s2s[o]     = *(const float4*)&s2[jbase + o];
        *(float4*)&s2s[o + 4] = *(const float4*)&s2[jbase + o + 4];
    }

    const u32* mrow = mask + (size_t)i_lane * 256 + (jbase >> 5);
    uint4 mgA = *(const uint4*)(mrow);
    uint4 mgB = *(const uint4*)(mrow + 4);

    floatx4 acc[4];
#pragma unroll
    for (int ct = 0; ct < 4; ct++) acc[ct] = (floatx4){0.f, 0.f, 0.f, 0.f};
    float Lacc = 0.f;
    const int quad2 = quad * 2;

    __syncthreads();   // s2s ready; no barriers after this

#pragma unroll 2
    for (int g = 0; g < 8; ++g) {                 // 8 groups of 256 j
        uint4 mgA_n = mgA, mgB_n = mgB;
        if (g + 1 < 8) {
            mgA_n = *(const uint4*)(mrow + (g + 1) * 8);
            mgB_n = *(const uint4*)(mrow + (g + 1) * 8 + 4);
        }
        const u32 mg[8] = {mgA.x, mgA.y, mgA.z, mgA.w, mgB.x, mgB.y, mgB.z, mgB.w};
#pragma unroll
        for (int p = 0; p < 2; ++p) {             // 2 chunks of 128 j per group
            const int jc = g * 2 + p;
            // --- issue this chunk's B-frag loads (16 x b128, L2-hot hT) ---
            short8 fb[16];
#pragma unroll
            for (int ct = 0; ct < 4; ++ct) {
                const u16* hr = hT + (size_t)((ch * 4 + ct) * 16 + n) * N_NODES
                              + jbase + jc * 128 + quad * 8;
#pragma unroll
                for (int ks = 0; ks < 4; ++ks)
                    fb[ct * 4 + ks] = *(const short8*)(hr + ks * 32);
            }
            // --- build A-frags (w weights) while B loads fly ---
            short8 fa[4];
#pragma unroll
            for (int ks = 0; ks < 4; ++ks) {
                const int jl = jc * 128 + ks * 32 + quad * 8;
                float4 sa = *(const float4*)&s2s[jl];
                float4 sb = *(const float4*)&s2s[jl + 4];
                const float sv[8] = {sa.x, sa.y, sa.z, sa.w, sb.x, sb.y, sb.z, sb.w};
                union { u32 u[4]; short8 s; } cv;
#pragma unroll
                for (int jh = 0; jh < 4; ++jh) {
                    float w2[2];
#pragma unroll
                    for (int e = 0; e < 2; ++e) {
                        const int jj = jh * 2 + e;
                        const u32 word = mg[(jj & 3) * 2 + p];
                        const u32 mbit = (word >> (ks * 8 + quad2 + (jj >> 2))) & 1u;
                        float sc = s1v + sv[jj];
                        sc = fmaxf(sc, LRELU_A * sc);
                        float w = mbit ? __expf(sc - MSH) : 0.f;
                        Lacc += w;
                        w2[e] = w;
                    }
                    cv.u[jh] = (u32)f2bf_rtn(w2[0]) | ((u32)f2bf_rtn(w2[1]) << 16);
                }
                fa[ks] = cv.s;
            }
            // --- 16 MFMAs ---
#pragma unroll
            for (int ks = 0; ks < 4; ++ks)
#pragma unroll
                for (int ct = 0; ct < 4; ++ct)
                    acc[ct] = __builtin_amdgcn_mfma_f32_16x16x32_bf16(fa[ks], fb[ct * 4 + ks], acc[ct], 0, 0, 0);
        }
        mgA = mgA_n; mgB = mgB_n;
    }

    // L row-sum across quads (both c-halves compute it; only ch==0 stores)
    Lacc += __shfl_xor(Lacc, 16, 64);
    Lacc += __shfl_xor(Lacc, 32, 64);
    if (ch == 0 && lane < 16)
        Lpart[(size_t)blockIdx.y * N_NODES + i_lane] = Lacc;

    // O partials (C layout: row = quad*4+reg, col = n)
    const size_t obase = (size_t)blockIdx.y * N_NODES * OUT_F;
#pragma unroll
    for (int ct = 0; ct < 4; ++ct) {
#pragma unroll
        for (int r = 0; r < 4; ++r) {
            const int i = i0 + ib * 16 + quad * 4 + r;
            Opart[obase + (size_t)i * OUT_F + (ch * 4 + ct) * 16 + n] = acc[ct][r];
        }
    }
}

// ---------------- combine partials, normalize, column stats via atomics ----------------
// grid 512 x 256 thr; block = 16 i-rows
__global__ __launch_bounds__(256) void k_comb(const float* __restrict__ Opart, const float* __restrict__ Lpart,
                                              float* __restrict__ hp, float* __restrict__ cs, float* __restrict__ cq) {
    const int t = threadIdx.x;
    const int c = t & 127, half = t >> 7;
    const int ibase = blockIdx.x * 16;
    float sv = 0.f, sq = 0.f;
    for (int k = 0; k < 8; k++) {
        const int i = ibase + half + (k << 1);
        float o = 0.f, L = 0.f;
#pragma unroll
        for (int s = 0; s < NSPLIT; s++) {
            o += Opart[((size_t)s * N_NODES + i) * OUT_F + c];
            L += Lpart[(size_t)s * N_NODES + i];
        }
        float v = L > 0.f ? o / L : 0.f;
        hp[(size_t)i * OUT_F + c] = v;
        sv += v; sq += v * v;
    }
    __shared__ float red[256];
    red[t] = sv; __syncthreads();
    if (half == 0) atomicAdd(&cs[c], sv + red[t + 128]);
    __syncthreads(); red[t] = sq; __syncthreads();
    if (half == 0) atomicAdd(&cq[c], sq + red[t + 128]);
}

// ---------------- batchnorm + elu + f32 out ----------------
__global__ __launch_bounds__(256) void k_bn(const float* __restrict__ hp, const float* __restrict__ cs,
                                            const float* __restrict__ cq, const float* __restrict__ gamma,
                                            const float* __restrict__ beta, float* __restrict__ out) {
    const int idx = blockIdx.x * 256 + threadIdx.x;   // 1M
    const int c = idx & 127;
    const float mean = cs[c] * (1.f / N_NODES);
    const float var  = cq[c] * (1.f / N_NODES) - mean * mean;
    float x = (hp[idx] - mean) * rsqrtf(var + EPS_BN) * gamma[c] + beta[c];
    x = x > 0.f ? x : expm1f(x);
    out[idx] = x;
}

extern "C" void kernel_launch(void* const* d_in, const int* in_sizes, int n_in,
                              void* d_out, int out_size, void* d_ws, size_t ws_size,
                              hipStream_t stream) {
    (void)in_sizes; (void)n_in; (void)out_size; (void)ws_size;
    const float* inp   = (const float*)d_in[0];
    const int*   adj   = (const int*)d_in[1];
    const float* W     = (const float*)d_in[2];
    const float* a     = (const float*)d_in[3];
    const float* gamma = (const float*)d_in[4];
    const float* beta  = (const float*)d_in[5];
    float* out = (float*)d_out;

    char* wsb = (char*)d_ws;
    u16*   hT   = (u16*)wsb;   wsb += (size_t)OUT_F * N_NODES * 2;            // 2 MB
    float* s1   = (float*)wsb; wsb += N_NODES * 4;
    float* s2   = (float*)wsb; wsb += N_NODES * 4;
    u32*   mask = (u32*)wsb;   wsb += (size_t)N_NODES * 256 * 4;              // 8 MB
    float* Op   = (float*)wsb; wsb += (size_t)NSPLIT * N_NODES * OUT_F * 4;   // 16 MB
    float* Lp   = (float*)wsb; wsb += (size_t)NSPLIT * N_NODES * 4;
    float* hp   = (float*)wsb; wsb += (size_t)N_NODES * OUT_F * 4;            // 4 MB
    float* cs   = (float*)wsb; wsb += OUT_F * 4;
    float* cq   = (float*)wsb; wsb += OUT_F * 4;

    hipLaunchKernelGGL(k_pack, dim3(2048), dim3(256), 0, stream, adj, mask);
    hipLaunchKernelGGL(k_h,    dim3(512), dim3(256), 0, stream, inp, W, a, hT, s1, s2, cs, cq);
    hipLaunchKernelGGL(k_att,  dim3(256, NSPLIT), dim3(256), 0, stream, mask, hT, s1, s2, Op, Lp);
    hipLaunchKernelGGL(k_comb, dim3(512), dim3(256), 0, stream, Op, Lp, hp, cs, cq);
    hipLaunchKernelGGL(k_bn,   dim3(4096), dim3(256), 0, stream, hp, cs, cq, gamma, beta, out);
}